// Round 4
// baseline (755.290 us; speedup 1.0000x reference)
//
#include <hip/hip_runtime.h>

#define TPB 256

// ---------------- LDS arena layout (float offsets) ----------------
// hpad_i @0: hpad0 [32][8][8]=2048, hpad1 [16][12][12]=2304,
//            hpad2 [8][20][20]=3200, hpad3 [4][36][36]=5184
// c_i (col-padded, stride H+4, data cols 1..H, col0/H+1 = edge dups):
//   c0 [16][4][8]  @2304..2816
//   c1 [8][8][12]  @4384..5152
//   c2 [4][16][20] @5552..6832
//   c3 [4][32][36] @5392..10000
// weights [co][ci][12] (9 used), row stride WS=CIN*12+4 (bank spread):
//   w0 16x388 @2816..9024 (loaded P1; dead after conv0)
//   w1  8x196 @2816..4384 (loaded during up0)
//   w2  4x100 @5152..5552 (loaded during up1)
//   w3  4x52  @5184..5392 (loaded during up2)
// misc: style[32]@10000, s[60]@10032 (s0+0,s1+32,s2+48,s3+56), d[32]@10092
constexpr int O_C0    = 2304;
constexpr int O_W0    = 2816;
constexpr int O_W1    = 2816;
constexpr int O_C1    = 4384;
constexpr int O_W2    = 5152;
constexpr int O_C2    = 5552;
constexpr int O_W3    = 5184;
constexpr int O_C3    = 5392;
constexpr int M_STYLE = 10000;
constexpr int M_S     = 10032;
constexpr int M_D     = 10092;
constexpr int LDSF    = 10124;   // 40496 B -> 4 blocks/CU

// 4-wide conv3x3: each thread computes a 4-col x R-row strip for one co.
template<int CIN, int COUT, int H, int R, int HS>
__device__ __forceinline__ void conv4(const float* __restrict__ hp,
                                      const float* __restrict__ wb,
                                      float* __restrict__ c, int tid)
{
    constexpr int XT = H/4, RS = H/R, NT = COUT*RS*XT;
    constexpr int WS = CIN*12 + 4;
    constexpr int PL = HS*HS;
    constexpr int CS = H + 4;
    constexpr int CP = H * CS;
    if (tid < NT) {
        const int t  = tid % XT;
        const int rs = (tid / XT) % RS;
        const int co = tid / (XT*RS);
        const int y0 = rs * R;
        const int x0 = 4*t;
        const float* wrow = wb + co*WS;
        float acc[R][4];
#pragma unroll
        for (int r = 0; r < R; r++) { acc[r][0]=acc[r][1]=acc[r][2]=acc[r][3]=0.f; }
        for (int ci = 0; ci < CIN; ci++) {
            const float* bp = hp + ci*PL + y0*HS + x0;
            float win[R+2][6];
#pragma unroll
            for (int rr = 0; rr < R+2; rr++) {
                const float4 a = *(const float4*)(bp + rr*HS);
                const float2 b = *(const float2*)(bp + rr*HS + 4);
                win[rr][0]=a.x; win[rr][1]=a.y; win[rr][2]=a.z; win[rr][3]=a.w;
                win[rr][4]=b.x; win[rr][5]=b.y;
            }
            const float4 wA = *(const float4*)(wrow + ci*12);
            const float4 wB = *(const float4*)(wrow + ci*12 + 4);
            const float  w8 = wrow[ci*12 + 8];
            const float wt[9] = {wA.x,wA.y,wA.z,wA.w,wB.x,wB.y,wB.z,wB.w,w8};
#pragma unroll
            for (int r = 0; r < R; r++)
#pragma unroll
                for (int dy = 0; dy < 3; dy++)
#pragma unroll
                    for (int dx = 0; dx < 3; dx++) {
                        const float wv = wt[dy*3+dx];
#pragma unroll
                        for (int j = 0; j < 4; j++)
                            acc[r][j] = fmaf(wv, win[r+dy][j+dx], acc[r][j]);
                    }
        }
        float* crow = c + co*CP + y0*CS + x0 + 1;   // padded col 4t+1
#pragma unroll
        for (int r = 0; r < R; r++) {
#pragma unroll
            for (int j = 0; j < 4; j++) crow[r*CS + j] = acc[r][j];
            if (t == 0)     crow[r*CS - 1] = acc[r][0];   // left edge dup
            if (t == XT-1)  crow[r*CS + 4] = acc[r][3];   // right edge dup
        }
    }
}

// 4-quad-wide bilinear x2 with demod; writes global float4 pairs and
// (if !LAST) s_next-modulated interior of hpad_{i+1} (scalar, odd offsets).
template<int COUT, int H, int KQ, bool LAST, int HSN>
__device__ __forceinline__ void up4(const float* __restrict__ c,
                                    const float* __restrict__ dmv,
                                    const float* __restrict__ snext,
                                    float* __restrict__ hnext,
                                    float* __restrict__ gout, int tid)
{
    constexpr int XT = H/4, KS = H/KQ, NT = COUT*KS*XT;
    constexpr int CS = H + 4, CP = H*CS;
    constexpr int PLN = HSN*HSN;
    if (tid < NT) {
        const int t  = tid % XT;
        const int ks = (tid / XT) % KS;
        const int co = tid / (XT*KS);
        const int k0 = ks*KQ;
        const float dm = dmv[co];
        float sn = 0.f;
        if constexpr (!LAST) sn = snext[co];
        const float* cb = c + co*CP + 4*t;
        float he[KQ+2][4], ho[KQ+2][4];
#pragma unroll
        for (int i = 0; i < KQ+2; i++) {
            int r = k0 - 1 + i; r = r < 0 ? 0 : (r > H-1 ? H-1 : r);
            const float4 a = *(const float4*)(cb + r*CS);
            const float2 b = *(const float2*)(cb + r*CS + 4);
            const float w0=a.x*dm, w1=a.y*dm, w2=a.z*dm, w3=a.w*dm, w4=b.x*dm, w5=b.y*dm;
            he[i][0]=0.25f*w0+0.75f*w1;  ho[i][0]=0.75f*w1+0.25f*w2;
            he[i][1]=0.25f*w1+0.75f*w2;  ho[i][1]=0.75f*w2+0.25f*w3;
            he[i][2]=0.25f*w2+0.75f*w3;  ho[i][2]=0.75f*w3+0.25f*w4;
            he[i][3]=0.25f*w3+0.75f*w4;  ho[i][3]=0.75f*w4+0.25f*w5;
        }
        float* gbase = gout + co*(4*H*H) + 8*t;
#pragma unroll
        for (int kk = 0; kk < KQ; kk++) {
            const int k = k0 + kk;
            float r0[8], r1[8];
#pragma unroll
            for (int j = 0; j < 4; j++) {
                r0[2*j]   = 0.25f*he[kk][j]   + 0.75f*he[kk+1][j];
                r0[2*j+1] = 0.25f*ho[kk][j]   + 0.75f*ho[kk+1][j];
                r1[2*j]   = 0.75f*he[kk+1][j] + 0.25f*he[kk+2][j];
                r1[2*j+1] = 0.75f*ho[kk+1][j] + 0.25f*ho[kk+2][j];
            }
            *(float4*)(gbase + (2*k)*(2*H))       = make_float4(r0[0],r0[1],r0[2],r0[3]);
            *(float4*)(gbase + (2*k)*(2*H) + 4)   = make_float4(r0[4],r0[5],r0[6],r0[7]);
            *(float4*)(gbase + (2*k+1)*(2*H))     = make_float4(r1[0],r1[1],r1[2],r1[3]);
            *(float4*)(gbase + (2*k+1)*(2*H) + 4) = make_float4(r1[4],r1[5],r1[6],r1[7]);
            if constexpr (!LAST) {
                float* hb = hnext + co*PLN + (2*k+1)*HSN + 8*t + 1;
#pragma unroll
                for (int j = 0; j < 8; j++) hb[j] = r0[j]*sn;
                hb += HSN;
#pragma unroll
                for (int j = 0; j < 8; j++) hb[j] = r1[j]*sn;
            }
        }
    }
}

template<int C, int DH, int HSN>   // DH = data rows/cols, halo at 0 and DH+1
__device__ __forceinline__ void zhalo(float* hp, int tid)
{
    constexpr int NR = C*HSN*2;
    for (int j = tid; j < NR; j += TPB) {
        const int ch = j / (2*HSN), rr = j % (2*HSN);
        const int row = (rr < HSN) ? 0 : DH+1;
        hp[ch*HSN*HSN + row*HSN + (rr % HSN)] = 0.f;
    }
    constexpr int NC = C*DH*2;
    for (int j = tid; j < NC; j += TPB) {
        const int ch = j / (2*DH), rr = j % (2*DH);
        const int col = (rr < DH) ? 0 : DH+1;
        hp[ch*HSN*HSN + (1 + (rr % DH))*HSN + col] = 0.f;
    }
}

template<int CIN, int COUT>
__device__ __forceinline__ void load_w(const float* __restrict__ g,
                                       float* __restrict__ wb, int tid)
{
    constexpr int N = COUT*CIN*9;
    constexpr int WS = CIN*12 + 4;
    for (int j = tid; j < N; j += TPB) {
        const int co = j / (CIN*9);
        const int r  = j - co*(CIN*9);
        const int ci = r / 9;
        const int k  = r - ci*9;
        wb[co*WS + ci*12 + k] = g[j];
    }
}

__global__ void __launch_bounds__(TPB, 4)
decoder_kernel(const float* __restrict__ x,   const float* __restrict__ fc_w,
               const float* __restrict__ fc_b,const float* __restrict__ cst,
               const float* __restrict__ cw0, const float* __restrict__ mw0, const float* __restrict__ mb0,
               const float* __restrict__ cw1, const float* __restrict__ mw1, const float* __restrict__ mb1,
               const float* __restrict__ cw2, const float* __restrict__ mw2, const float* __restrict__ mb2,
               const float* __restrict__ cw3, const float* __restrict__ mw3, const float* __restrict__ mb3,
               float* __restrict__ f0, float* __restrict__ f1,
               float* __restrict__ f2, float* __restrict__ f3)
{
    __shared__ float lds[LDSF];
    const int tid = threadIdx.x;
    const int b   = blockIdx.x;

    // P0: style = x @ fc_w.T + fc_b
    if (tid < 32) {
        const float* xr = x + (size_t)b*32;
        const float* fw = fc_w + tid*32;
        float acc = fc_b[tid];
#pragma unroll
        for (int k = 0; k < 32; k++) acc = fmaf(xr[k], fw[k], acc);
        lds[M_STYLE + tid] = acc;
    }
    __syncthreads();

    // P1: s_all (60) + stage w0
    if (tid < 60) {
        int ci; const float* mwp; const float* mbp;
        if (tid < 32)      { ci = tid;      mwp = mw0; mbp = mb0; }
        else if (tid < 48) { ci = tid - 32; mwp = mw1; mbp = mb1; }
        else if (tid < 56) { ci = tid - 48; mwp = mw2; mbp = mb2; }
        else               { ci = tid - 56; mwp = mw3; mbp = mb3; }
        mwp += ci*32;
        float acc = mbp[ci];
#pragma unroll
        for (int k = 0; k < 32; k++) acc = fmaf(lds[M_STYLE + k], mwp[k], acc);
        lds[M_S + tid] = acc;
    }
    load_w<32,16>(cw0, &lds[O_W0], tid);
    __syncthreads();

    // P2: demod (32 groups x 8 lanes, reads global weights) + hpad0 init
    {
        const int g = tid >> 3, l = tid & 7;
        int co, cin; const float* wp; const float* sp;
        if (g < 16)      { co = g;      cin = 32; wp = cw0; sp = &lds[M_S];      }
        else if (g < 24) { co = g - 16; cin = 16; wp = cw1; sp = &lds[M_S + 32]; }
        else if (g < 28) { co = g - 24; cin = 8;  wp = cw2; sp = &lds[M_S + 48]; }
        else             { co = g - 28; cin = 4;  wp = cw3; sp = &lds[M_S + 56]; }
        wp += co*cin*9;
        float acc = 0.f;
        for (int e = l; e < cin*9; e += 8) {
            const int ci = e / 9;
            const float wv = wp[e] * sp[ci];
            acc = fmaf(wv, wv, acc);
        }
        acc += __shfl_xor(acc, 1);
        acc += __shfl_xor(acc, 2);
        acc += __shfl_xor(acc, 4);
        if (l == 0) lds[M_D + g] = rsqrtf(acc + 1e-8f);
    }
    for (int j = tid; j < 2048; j += TPB) {          // hpad0 [32][8][8]
        const int ci = j >> 6, r = j & 63, y = r >> 3, xx = r & 7;
        float v = 0.f;
        if (y >= 1 && y <= 4 && xx >= 1 && xx <= 4)
            v = lds[M_S + ci] * cst[ci*16 + (y-1)*4 + (xx-1)];
        lds[j] = v;
    }
    __syncthreads();

    // ---- layer 0 ----
    conv4<32,16,4,1,8>(&lds[0], &lds[O_W0], &lds[O_C0], tid);
    __syncthreads();
    up4<16,4,1,false,12>(&lds[O_C0], &lds[M_D], &lds[M_S+32], &lds[0],
                         f0 + (size_t)b*1024, tid);
    zhalo<16,8,12>(&lds[0], tid);
    load_w<16,8>(cw1, &lds[O_W1], tid);
    __syncthreads();

    // ---- layer 1 ----
    conv4<16,8,8,1,12>(&lds[0], &lds[O_W1], &lds[O_C1], tid);
    __syncthreads();
    up4<8,8,1,false,20>(&lds[O_C1], &lds[M_D+16], &lds[M_S+48], &lds[0],
                        f1 + (size_t)b*2048, tid);
    zhalo<8,16,20>(&lds[0], tid);
    load_w<8,4>(cw2, &lds[O_W2], tid);
    __syncthreads();

    // ---- layer 2 ----
    conv4<8,4,16,1,20>(&lds[0], &lds[O_W2], &lds[O_C2], tid);
    __syncthreads();
    up4<4,16,1,false,36>(&lds[O_C2], &lds[M_D+24], &lds[M_S+56], &lds[0],
                         f2 + (size_t)b*4096, tid);
    zhalo<4,32,36>(&lds[0], tid);
    load_w<4,4>(cw3, &lds[O_W3], tid);
    __syncthreads();

    // ---- layer 3 ----
    conv4<4,4,32,4,36>(&lds[0], &lds[O_W3], &lds[O_C3], tid);
    __syncthreads();
    up4<4,32,4,true,1>(&lds[O_C3], &lds[M_D+28], nullptr, nullptr,
                       f3 + (size_t)b*16384, tid);
}

extern "C" void kernel_launch(void* const* d_in, const int* in_sizes, int n_in,
                              void* d_out, int out_size, void* d_ws, size_t ws_size,
                              hipStream_t stream)
{
    const float* x    = (const float*)d_in[0];
    const float* fc_w = (const float*)d_in[1];
    const float* fc_b = (const float*)d_in[2];
    const float* cst  = (const float*)d_in[3];
    const float* cw0  = (const float*)d_in[4];
    const float* mw0  = (const float*)d_in[5];
    const float* mb0  = (const float*)d_in[6];
    const float* cw1  = (const float*)d_in[7];
    const float* mw1  = (const float*)d_in[8];
    const float* mb1  = (const float*)d_in[9];
    const float* cw2  = (const float*)d_in[10];
    const float* mw2  = (const float*)d_in[11];
    const float* mb2  = (const float*)d_in[12];
    const float* cw3  = (const float*)d_in[13];
    const float* mw3  = (const float*)d_in[14];
    const float* mb3  = (const float*)d_in[15];
    float* out = (float*)d_out;

    const int Bn = in_sizes[0] / 32;                 // 4096
    float* f0 = out;
    float* f1 = f0 + (size_t)Bn*1024;
    float* f2 = f1 + (size_t)Bn*2048;
    float* f3 = f2 + (size_t)Bn*4096;

    decoder_kernel<<<dim3(Bn), dim3(TPB), 0, stream>>>(
        x, fc_w, fc_b, cst,
        cw0, mw0, mb0, cw1, mw1, mb1, cw2, mw2, mb2, cw3, mw3, mb3,
        f0, f1, f2, f3);
}